// Round 4
// baseline (251.893 us; speedup 1.0000x reference)
//
#include <hip/hip_runtime.h>

// Problem constants
#define Bn  4
#define Cn  128
#define CQn 64
#define Nn  4096

typedef _Float16 h8_t __attribute__((ext_vector_type(8)));
typedef float    f32x4 __attribute__((ext_vector_type(4)));
typedef unsigned int u32;
typedef u32      u32x2 __attribute__((ext_vector_type(2)));

// ws layout (halves):
//  Qh: [B][N][64]   offset 0        (1,048,576)
//  Kh: [B][N][64]   offset 1048576  (1,048,576)
//  Vt: [B][128][N]  offset 2097152  (2,097,152)   (V transposed: [C][N])

// ---------------------------------------------------------------------------
// Kernel 1: fused QKV projection (fp32 compute, f16 outputs in attn layouts)
// ---------------------------------------------------------------------------
__global__ __launch_bounds__(256) void qkv_proj(
    const float* __restrict__ x,
    const float* __restrict__ Wq, const float* __restrict__ bq,
    const float* __restrict__ Wk, const float* __restrict__ bk,
    const float* __restrict__ Wv, const float* __restrict__ bv,
    _Float16* __restrict__ Qh, _Float16* __restrict__ Kh, _Float16* __restrict__ Vt)
{
    const int ntile = blockIdx.x;
    const int otile = blockIdx.y;
    const int b     = blockIdx.z;
    const int tid   = threadIdx.x;
    const int nbase = ntile * 64;

    __shared__ float Ws[64][132];
    __shared__ float Xs[128][68];

    const float* Wsrc; const float* bsrc; int obase;
    if (otile == 0)      { Wsrc = Wq;                     bsrc = bq;      obase = 0; }
    else if (otile == 1) { Wsrc = Wk;                     bsrc = bk;      obase = 0; }
    else                 { Wsrc = Wv + (otile - 2) * 64 * Cn;
                           bsrc = bv + (otile - 2) * 64;  obase = (otile - 2) * 64; }

    for (int u = 0; u < 8; ++u) {
        int f = tid + u * 256;
        int row = f >> 5;
        int col = (f & 31) * 4;
        *(float4*)&Ws[row][col] = *(const float4*)&Wsrc[row * Cn + col];
    }
    const float* xb = x + ((size_t)b * Cn) * Nn + nbase;
    for (int u = 0; u < 8; ++u) {
        int f = tid + u * 256;
        int c = f >> 4;
        int n = (f & 15) * 4;
        *(float4*)&Xs[c][n] = *(const float4*)&xb[(size_t)c * Nn + n];
    }
    __syncthreads();

    const int o0 = (tid >> 4) * 4;
    const int n0 = (tid & 15) * 4;
    float acc[4][4] = {};

    for (int c = 0; c < Cn; c += 4) {
        float4 w4[4], x4[4];
        for (int oo = 0; oo < 4; ++oo) w4[oo] = *(const float4*)&Ws[o0 + oo][c];
        for (int cc = 0; cc < 4; ++cc) x4[cc] = *(const float4*)&Xs[c + cc][n0];
        for (int oo = 0; oo < 4; ++oo) {
            const float* wv = (const float*)&w4[oo];
            for (int cc = 0; cc < 4; ++cc) {
                const float wsv = wv[cc];
                const float* xp = (const float*)&x4[cc];
                acc[oo][0] += wsv * xp[0];
                acc[oo][1] += wsv * xp[1];
                acc[oo][2] += wsv * xp[2];
                acc[oo][3] += wsv * xp[3];
            }
        }
    }

    float bias[4];
    for (int oo = 0; oo < 4; ++oo) bias[oo] = bsrc[o0 + oo];

    union H4 { _Float16 e[4]; short4 v; };

    if (otile <= 1) {
        _Float16* dst = (otile == 0 ? Qh : Kh) + ((size_t)b * Nn + nbase) * CQn;
        for (int nn = 0; nn < 4; ++nn) {
            H4 h;
            for (int oo = 0; oo < 4; ++oo) h.e[oo] = (_Float16)(acc[oo][nn] + bias[oo]);
            *(short4*)&dst[(size_t)(n0 + nn) * CQn + o0] = h.v;
        }
    } else {
        _Float16* dst = Vt + (size_t)b * Cn * Nn;
        const int og = obase + o0;
        for (int oo = 0; oo < 4; ++oo) {
            H4 h;
            for (int nn = 0; nn < 4; ++nn) h.e[nn] = (_Float16)(acc[oo][nn] + bias[oo]);
            *(short4*)&dst[(size_t)(og + oo) * Nn + nbase + n0] = h.v;
        }
    }
}

// ---------------------------------------------------------------------------
// Kernel 2: MFMA flash attention with intra-block 4-way KV split.
// 1024 threads = 16 waves = 4 query-waves (qw) x 4 splits (s).
// Wave (qw,s): queries [blk*64 + 16qw, +16), j-tiles [16s, 16s+16).
// Swapped QK^T (D = S^T, col=query=ln). PV pairs P and V through the same
// kappa(e,g) slot map (correct for any HW k-map). End: 2-round LDS tree
// combine of (m, l, oacc) across splits, s=0 writes out.
// Dynamic LDS: 4 x 17408 B V buffers; combine overlays the same memory.
// ---------------------------------------------------------------------------
__device__ __forceinline__ h8_t mkb(u32x2 lo, u32x2 hi) {
    union { h8_t h; u32 u[4]; } t;
    t.u[0] = lo[0]; t.u[1] = lo[1]; t.u[2] = hi[0]; t.u[3] = hi[1];
    return t.h;
}

#define VS_STRIDE 136            // bytes per V row (68 halves)
#define VS_BUFB   17408          // 128 * 136
#define ML_OFF    65536          // ml scratch offset (overlays Vs buf 3 tail)

__global__ __launch_bounds__(1024) void attn_mfma(
    const _Float16* __restrict__ Qh, const _Float16* __restrict__ Kh,
    const _Float16* __restrict__ Vt, float* __restrict__ out)
{
    extern __shared__ __align__(16) char smem[];

    const int tid  = threadIdx.x;
    const int w    = tid >> 6;
    const int qw   = w & 3;          // query-wave
    const int s    = w >> 2;         // kv split
    const int lane = tid & 63;
    const int g    = lane >> 4;
    const int ln   = lane & 15;
    const int b    = blockIdx.y;
    const int wib  = blockIdx.x * 64 + qw * 16;

    char* VsB = smem + s * VS_BUFB;  // this split's V buffer

    // Persistent Q fragments (B operand: col=ln -> query wib+ln)
    const _Float16* qrow = Qh + ((size_t)(b * Nn + wib + ln)) * CQn + 8 * g;
    const h8_t q0 = *(const h8_t*)(qrow);
    const h8_t q1 = *(const h8_t*)(qrow + 32);

    const _Float16* Kb  = Kh + (size_t)b * Nn * CQn;
    const _Float16* Vtb = Vt + (size_t)b * Cn * Nn;

    f32x4 oacc[8];
    #pragma unroll
    for (int i = 0; i < 8; ++i) oacc[i] = (f32x4){0.f, 0.f, 0.f, 0.f};
    float m_run = -3.0e38f, l_run = 0.f;

    h8_t kfA[4][2], kfB[4][2];

    auto loadK = [&](h8_t (&kf)[4][2], int jt) {
        const _Float16* kbase = Kb + ((size_t)(jt * 64 + ln)) * CQn + 8 * g;
        #pragma unroll
        for (int js = 0; js < 4; ++js) {
            kf[js][0] = *(const h8_t*)(kbase + js * 16 * CQn);
            kf[js][1] = *(const h8_t*)(kbase + js * 16 * CQn + 32);
        }
    };

    // V staging coords within this split group (4 waves = 256 threads)
    const int gtid = qw * 64 + lane;

    auto tile = [&](h8_t (&kfU)[4][2], h8_t (&kfN)[4][2], int jt) {
        const int jbase = jt * 64;

        // 1) issue V-stage global loads early (latency hides under scores)
        float4 vr[4];
        const _Float16* vg = Vtb + jbase;
        #pragma unroll
        for (int u = 0; u < 4; ++u) {
            int f = gtid + u * 256;
            vr[u] = *(const float4*)(vg + (size_t)(f >> 3) * Nn + (f & 7) * 8);
        }

        // 2) prefetch next K tile into registers
        loadK(kfN, (jt + 1) & 63);

        // 3) scores: st[js] rows = keys js*16+4g+r, col = query ln
        f32x4 st[4];
        #pragma unroll
        for (int js = 0; js < 4; ++js) {
            st[js] = (f32x4){0.f, 0.f, 0.f, 0.f};
            st[js] = __builtin_amdgcn_mfma_f32_16x16x32_f16(kfU[js][0], q0, st[js], 0, 0, 0);
            st[js] = __builtin_amdgcn_mfma_f32_16x16x32_f16(kfU[js][1], q1, st[js], 0, 0, 0);
        }

        // 4) online softmax (per query = per ln, replicated over g)
        float tmax = st[0][0];
        #pragma unroll
        for (int js = 0; js < 4; ++js)
            #pragma unroll
            for (int r = 0; r < 4; ++r) tmax = fmaxf(tmax, st[js][r]);
        tmax = fmaxf(tmax, __shfl_xor(tmax, 16));
        tmax = fmaxf(tmax, __shfl_xor(tmax, 32));
        const float mnew = fmaxf(m_run, tmax);
        float ts = 0.f;
        #pragma unroll
        for (int js = 0; js < 4; ++js)
            #pragma unroll
            for (int r = 0; r < 4; ++r) {
                float p = __expf(st[js][r] - mnew);
                st[js][r] = p;
                ts += p;
            }
        ts += __shfl_xor(ts, 16);
        ts += __shfl_xor(ts, 32);
        const float alpha = __expf(m_run - mnew);
        l_run = l_run * alpha + ts;
        m_run = mnew;

        const float a0 = __shfl(alpha, 4 * g + 0);
        const float a1 = __shfl(alpha, 4 * g + 1);
        const float a2 = __shfl(alpha, 4 * g + 2);
        const float a3 = __shfl(alpha, 4 * g + 3);
        #pragma unroll
        for (int cs = 0; cs < 8; ++cs) {
            oacc[cs][0] *= a0; oacc[cs][1] *= a1;
            oacc[cs][2] *= a2; oacc[cs][3] *= a3;
        }

        // P fragments by kappa(e,g) = 4g+(e&3)+16*(e>>2)
        union H8 { h8_t h; _Float16 e[8]; };
        H8 p0u, p1u;
        #pragma unroll
        for (int r = 0; r < 4; ++r) {
            p0u.e[r]     = (_Float16)st[0][r];
            p0u.e[4 + r] = (_Float16)st[1][r];
            p1u.e[r]     = (_Float16)st[2][r];
            p1u.e[4 + r] = (_Float16)st[3][r];
        }
        const h8_t pa0 = p0u.h;
        const h8_t pa1 = p1u.h;

        // 5) stage V tile into this split's LDS buffer
        __syncthreads();
        #pragma unroll
        for (int u = 0; u < 4; ++u) {
            int f = gtid + u * 256;
            *(float4*)(VsB + (size_t)(f >> 3) * VS_STRIDE + (f & 7) * 16) = vr[u];
        }
        __syncthreads();

        // 6) PV: per c-subtile, gather B-fragments by the same kappa map
        #pragma unroll
        for (int cs = 0; cs < 8; ++cs) {
            const char* vrow = VsB + (size_t)(cs * 16 + ln) * VS_STRIDE;
            u32x2 a0v = *(const u32x2*)(vrow + (4 * g) * 2);
            u32x2 a1v = *(const u32x2*)(vrow + (4 * g + 16) * 2);
            u32x2 b0v = *(const u32x2*)(vrow + (4 * g + 32) * 2);
            u32x2 b1v = *(const u32x2*)(vrow + (4 * g + 48) * 2);
            oacc[cs] = __builtin_amdgcn_mfma_f32_16x16x32_f16(pa0, mkb(a0v, a1v), oacc[cs], 0, 0, 0);
            oacc[cs] = __builtin_amdgcn_mfma_f32_16x16x32_f16(pa1, mkb(b0v, b1v), oacc[cs], 0, 0, 0);
        }
    };

    const int jt0 = s * 16;
    loadK(kfA, jt0);
    for (int t = 0; t < 16; t += 2) {
        tile(kfA, kfB, jt0 + t);
        tile(kfB, kfA, jt0 + t + 1);
    }

    // ---- combine partials across splits (2-round LDS tree) ----
    // slot k (0..7): oacc at smem + k*8192 (cs*1024 + lane*16 layout);
    // m,l at smem + ML_OFF + k*128 (m: ln*4, l: 64 + ln*4).
    auto storeSlot = [&](int k) {
        float* sp = (float*)(smem + k * 8192);
        #pragma unroll
        for (int cs = 0; cs < 8; ++cs)
            *(f32x4*)(sp + cs * 256 + lane * 4) = oacc[cs];
        if (g == 0) {
            float* mlp = (float*)(smem + ML_OFF + k * 128);
            mlp[ln] = m_run;
            mlp[16 + ln] = l_run;
        }
    };
    auto mergeSlot = [&](int k) {
        const float* sp  = (const float*)(smem + k * 8192);
        const float* mlp = (const float*)(smem + ML_OFF + k * 128);
        const float mb = mlp[ln];
        const float lb = mlp[16 + ln];
        const float mn = fmaxf(m_run, mb);
        const float fa = __expf(m_run - mn);
        const float fb = __expf(mb - mn);
        l_run = fa * l_run + fb * lb;
        m_run = mn;
        const float fa0 = __shfl(fa, 4 * g + 0), fb0 = __shfl(fb, 4 * g + 0);
        const float fa1 = __shfl(fa, 4 * g + 1), fb1 = __shfl(fb, 4 * g + 1);
        const float fa2 = __shfl(fa, 4 * g + 2), fb2 = __shfl(fb, 4 * g + 2);
        const float fa3 = __shfl(fa, 4 * g + 3), fb3 = __shfl(fb, 4 * g + 3);
        #pragma unroll
        for (int cs = 0; cs < 8; ++cs) {
            f32x4 ob = *(const f32x4*)(sp + cs * 256 + lane * 4);
            oacc[cs][0] = fa0 * oacc[cs][0] + fb0 * ob[0];
            oacc[cs][1] = fa1 * oacc[cs][1] + fb1 * ob[1];
            oacc[cs][2] = fa2 * oacc[cs][2] + fb2 * ob[2];
            oacc[cs][3] = fa3 * oacc[cs][3] + fb3 * ob[3];
        }
    };

    __syncthreads();                       // Vs buffers dead from here
    if (s >= 2) storeSlot((s - 2) * 4 + qw);
    __syncthreads();
    if (s < 2)  mergeSlot(s * 4 + qw);
    __syncthreads();
    if (s == 1) storeSlot(qw);
    __syncthreads();
    if (s == 0) {
        mergeSlot(qw);
        // Epilogue: out[b][c][i], rows i = wib+4g+r, col c = cs*16+ln
        const float lr = 1.f / l_run;
        const float l0 = __shfl(lr, 4 * g + 0);
        const float l1 = __shfl(lr, 4 * g + 1);
        const float l2 = __shfl(lr, 4 * g + 2);
        const float l3 = __shfl(lr, 4 * g + 3);
        float* ob = out + (size_t)b * Cn * Nn;
        #pragma unroll
        for (int cs = 0; cs < 8; ++cs) {
            float4 o;
            o.x = oacc[cs][0] * l0;
            o.y = oacc[cs][1] * l1;
            o.z = oacc[cs][2] * l2;
            o.w = oacc[cs][3] * l3;
            *(float4*)&ob[(size_t)(cs * 16 + ln) * Nn + wib + 4 * g] = o;
        }
    }
}

extern "C" void kernel_launch(void* const* d_in, const int* in_sizes, int n_in,
                              void* d_out, int out_size, void* d_ws, size_t ws_size,
                              hipStream_t stream) {
    const float* x  = (const float*)d_in[0];
    const float* Wq = (const float*)d_in[1];
    const float* bq = (const float*)d_in[2];
    const float* Wk = (const float*)d_in[3];
    const float* bk = (const float*)d_in[4];
    const float* Wv = (const float*)d_in[5];
    const float* bv = (const float*)d_in[6];
    float* out = (float*)d_out;

    _Float16* ws = (_Float16*)d_ws;
    _Float16* Qh = ws;
    _Float16* Kh = ws + 1048576;
    _Float16* Vt = ws + 2097152;

    dim3 gproj(Nn / 64, 4, Bn);
    qkv_proj<<<gproj, 256, 0, stream>>>(x, Wq, bq, Wk, bk, Wv, bv, Qh, Kh, Vt);

    dim3 gattn(Nn / 64, Bn);
    attn_mfma<<<gattn, 1024, 4 * VS_BUFB, stream>>>(Qh, Kh, Vt, out);
}

// Round 5
// 251.465 us; speedup vs baseline: 1.0017x; 1.0017x over previous
//
#include <hip/hip_runtime.h>

// Problem constants
#define Bn  4
#define Cn  128
#define CQn 64
#define Nn  4096

typedef _Float16 h8_t __attribute__((ext_vector_type(8)));
typedef float    f32x4 __attribute__((ext_vector_type(4)));
typedef unsigned int u32;
typedef u32      u32x2 __attribute__((ext_vector_type(2)));

// ws layout (halves):
//  Qh: [B][N][64]   offset 0        (1,048,576)
//  Kh: [B][N][64]   offset 1048576  (1,048,576)
//  Vt: [B][128][N]  offset 2097152  (2,097,152)   (V transposed: [C][N])

// ---------------------------------------------------------------------------
// Kernel 1: fused QKV projection (fp32 compute, f16 outputs in attn layouts)
// ---------------------------------------------------------------------------
__global__ __launch_bounds__(256) void qkv_proj(
    const float* __restrict__ x,
    const float* __restrict__ Wq, const float* __restrict__ bq,
    const float* __restrict__ Wk, const float* __restrict__ bk,
    const float* __restrict__ Wv, const float* __restrict__ bv,
    _Float16* __restrict__ Qh, _Float16* __restrict__ Kh, _Float16* __restrict__ Vt)
{
    const int ntile = blockIdx.x;
    const int otile = blockIdx.y;
    const int b     = blockIdx.z;
    const int tid   = threadIdx.x;
    const int nbase = ntile * 64;

    __shared__ float Ws[64][132];
    __shared__ float Xs[128][68];

    const float* Wsrc; const float* bsrc; int obase;
    if (otile == 0)      { Wsrc = Wq;                     bsrc = bq;      obase = 0; }
    else if (otile == 1) { Wsrc = Wk;                     bsrc = bk;      obase = 0; }
    else                 { Wsrc = Wv + (otile - 2) * 64 * Cn;
                           bsrc = bv + (otile - 2) * 64;  obase = (otile - 2) * 64; }

    for (int u = 0; u < 8; ++u) {
        int f = tid + u * 256;
        int row = f >> 5;
        int col = (f & 31) * 4;
        *(float4*)&Ws[row][col] = *(const float4*)&Wsrc[row * Cn + col];
    }
    const float* xb = x + ((size_t)b * Cn) * Nn + nbase;
    for (int u = 0; u < 8; ++u) {
        int f = tid + u * 256;
        int c = f >> 4;
        int n = (f & 15) * 4;
        *(float4*)&Xs[c][n] = *(const float4*)&xb[(size_t)c * Nn + n];
    }
    __syncthreads();

    const int o0 = (tid >> 4) * 4;
    const int n0 = (tid & 15) * 4;
    float acc[4][4] = {};

    for (int c = 0; c < Cn; c += 4) {
        float4 w4[4], x4[4];
        for (int oo = 0; oo < 4; ++oo) w4[oo] = *(const float4*)&Ws[o0 + oo][c];
        for (int cc = 0; cc < 4; ++cc) x4[cc] = *(const float4*)&Xs[c + cc][n0];
        for (int oo = 0; oo < 4; ++oo) {
            const float* wv = (const float*)&w4[oo];
            for (int cc = 0; cc < 4; ++cc) {
                const float wsv = wv[cc];
                const float* xp = (const float*)&x4[cc];
                acc[oo][0] += wsv * xp[0];
                acc[oo][1] += wsv * xp[1];
                acc[oo][2] += wsv * xp[2];
                acc[oo][3] += wsv * xp[3];
            }
        }
    }

    float bias[4];
    for (int oo = 0; oo < 4; ++oo) bias[oo] = bsrc[o0 + oo];

    union H4 { _Float16 e[4]; short4 v; };

    if (otile <= 1) {
        _Float16* dst = (otile == 0 ? Qh : Kh) + ((size_t)b * Nn + nbase) * CQn;
        for (int nn = 0; nn < 4; ++nn) {
            H4 h;
            for (int oo = 0; oo < 4; ++oo) h.e[oo] = (_Float16)(acc[oo][nn] + bias[oo]);
            *(short4*)&dst[(size_t)(n0 + nn) * CQn + o0] = h.v;
        }
    } else {
        _Float16* dst = Vt + (size_t)b * Cn * Nn;
        const int og = obase + o0;
        for (int oo = 0; oo < 4; ++oo) {
            H4 h;
            for (int nn = 0; nn < 4; ++nn) h.e[nn] = (_Float16)(acc[oo][nn] + bias[oo]);
            *(short4*)&dst[(size_t)(og + oo) * Nn + nbase + n0] = h.v;
        }
    }
}

// ---------------------------------------------------------------------------
// Kernel 2: MFMA flash attention with intra-block 4-way KV split.
// 1024 threads = 16 waves = 4 query-waves (qw) x 4 splits (s).
// __launch_bounds__(1024, 4): 4 waves/EU -> VGPR cap 128 (round 4's implicit
// 64-cap spilled ~110 live regs -> 768 MB scratch traffic; this is the fix).
// Wave (qw,s): queries [blk*64 + 16qw, +16), j-tiles [16s, 16s+16).
// Swapped QK^T (D = S^T, col=query=ln). PV pairs P and V through the same
// kappa(e,g) slot map (correct for any HW k-map). End: 2-round LDS tree
// combine of (m, l, oacc) across splits, s=0 writes out.
// Dynamic LDS: 4 x 17408 B V buffers; combine overlays the same memory.
// ---------------------------------------------------------------------------
__device__ __forceinline__ h8_t mkb(u32x2 lo, u32x2 hi) {
    union { h8_t h; u32 u[4]; } t;
    t.u[0] = lo[0]; t.u[1] = lo[1]; t.u[2] = hi[0]; t.u[3] = hi[1];
    return t.h;
}

#define VS_STRIDE 136            // bytes per V row (68 halves)
#define VS_BUFB   17408          // 128 * 136
#define ML_OFF    65536          // ml scratch offset (overlays Vs buf 3 tail)

__global__ __launch_bounds__(1024, 4) void attn_mfma(
    const _Float16* __restrict__ Qh, const _Float16* __restrict__ Kh,
    const _Float16* __restrict__ Vt, float* __restrict__ out)
{
    extern __shared__ __align__(16) char smem[];

    const int tid  = threadIdx.x;
    const int w    = tid >> 6;
    const int qw   = w & 3;          // query-wave
    const int s    = w >> 2;         // kv split
    const int lane = tid & 63;
    const int g    = lane >> 4;
    const int ln   = lane & 15;
    const int b    = blockIdx.y;
    const int wib  = blockIdx.x * 64 + qw * 16;

    char* VsB = smem + s * VS_BUFB;  // this split's V buffer

    // Persistent Q fragments (B operand: col=ln -> query wib+ln)
    const _Float16* qrow = Qh + ((size_t)(b * Nn + wib + ln)) * CQn + 8 * g;
    const h8_t q0 = *(const h8_t*)(qrow);
    const h8_t q1 = *(const h8_t*)(qrow + 32);

    const _Float16* Kb  = Kh + (size_t)b * Nn * CQn;
    const _Float16* Vtb = Vt + (size_t)b * Cn * Nn;

    f32x4 oacc[8];
    #pragma unroll
    for (int i = 0; i < 8; ++i) oacc[i] = (f32x4){0.f, 0.f, 0.f, 0.f};
    float m_run = -3.0e38f, l_run = 0.f;

    h8_t kfA[4][2], kfB[4][2];

    auto loadK = [&](h8_t (&kf)[4][2], int jt) {
        const _Float16* kbase = Kb + ((size_t)(jt * 64 + ln)) * CQn + 8 * g;
        #pragma unroll
        for (int js = 0; js < 4; ++js) {
            kf[js][0] = *(const h8_t*)(kbase + js * 16 * CQn);
            kf[js][1] = *(const h8_t*)(kbase + js * 16 * CQn + 32);
        }
    };

    // V staging coords within this split group (4 waves = 256 threads)
    const int gtid = qw * 64 + lane;

    auto tile = [&](h8_t (&kfU)[4][2], h8_t (&kfN)[4][2], int jt) {
        const int jbase = jt * 64;

        // 1) issue V-stage global loads early (latency hides under scores)
        float4 vr[4];
        const _Float16* vg = Vtb + jbase;
        #pragma unroll
        for (int u = 0; u < 4; ++u) {
            int f = gtid + u * 256;
            vr[u] = *(const float4*)(vg + (size_t)(f >> 3) * Nn + (f & 7) * 8);
        }

        // 2) prefetch next K tile into registers
        loadK(kfN, (jt + 1) & 63);

        // 3) scores: st[js] rows = keys js*16+4g+r, col = query ln
        f32x4 st[4];
        #pragma unroll
        for (int js = 0; js < 4; ++js) {
            st[js] = (f32x4){0.f, 0.f, 0.f, 0.f};
            st[js] = __builtin_amdgcn_mfma_f32_16x16x32_f16(kfU[js][0], q0, st[js], 0, 0, 0);
            st[js] = __builtin_amdgcn_mfma_f32_16x16x32_f16(kfU[js][1], q1, st[js], 0, 0, 0);
        }

        // 4) online softmax (per query = per ln, replicated over g)
        float tmax = st[0][0];
        #pragma unroll
        for (int js = 0; js < 4; ++js)
            #pragma unroll
            for (int r = 0; r < 4; ++r) tmax = fmaxf(tmax, st[js][r]);
        tmax = fmaxf(tmax, __shfl_xor(tmax, 16));
        tmax = fmaxf(tmax, __shfl_xor(tmax, 32));
        const float mnew = fmaxf(m_run, tmax);
        float ts = 0.f;
        #pragma unroll
        for (int js = 0; js < 4; ++js)
            #pragma unroll
            for (int r = 0; r < 4; ++r) {
                float p = __expf(st[js][r] - mnew);
                st[js][r] = p;
                ts += p;
            }
        ts += __shfl_xor(ts, 16);
        ts += __shfl_xor(ts, 32);
        const float alpha = __expf(m_run - mnew);
        l_run = l_run * alpha + ts;
        m_run = mnew;

        const float a0 = __shfl(alpha, 4 * g + 0);
        const float a1 = __shfl(alpha, 4 * g + 1);
        const float a2 = __shfl(alpha, 4 * g + 2);
        const float a3 = __shfl(alpha, 4 * g + 3);
        #pragma unroll
        for (int cs = 0; cs < 8; ++cs) {
            oacc[cs][0] *= a0; oacc[cs][1] *= a1;
            oacc[cs][2] *= a2; oacc[cs][3] *= a3;
        }

        // P fragments by kappa(e,g) = 4g+(e&3)+16*(e>>2)
        union H8 { h8_t h; _Float16 e[8]; };
        H8 p0u, p1u;
        #pragma unroll
        for (int r = 0; r < 4; ++r) {
            p0u.e[r]     = (_Float16)st[0][r];
            p0u.e[4 + r] = (_Float16)st[1][r];
            p1u.e[r]     = (_Float16)st[2][r];
            p1u.e[4 + r] = (_Float16)st[3][r];
        }
        const h8_t pa0 = p0u.h;
        const h8_t pa1 = p1u.h;

        // 5) stage V tile into this split's LDS buffer
        __syncthreads();
        #pragma unroll
        for (int u = 0; u < 4; ++u) {
            int f = gtid + u * 256;
            *(float4*)(VsB + (size_t)(f >> 3) * VS_STRIDE + (f & 7) * 16) = vr[u];
        }
        __syncthreads();

        // 6) PV: per c-subtile, gather B-fragments by the same kappa map
        #pragma unroll
        for (int cs = 0; cs < 8; ++cs) {
            const char* vrow = VsB + (size_t)(cs * 16 + ln) * VS_STRIDE;
            u32x2 a0v = *(const u32x2*)(vrow + (4 * g) * 2);
            u32x2 a1v = *(const u32x2*)(vrow + (4 * g + 16) * 2);
            u32x2 b0v = *(const u32x2*)(vrow + (4 * g + 32) * 2);
            u32x2 b1v = *(const u32x2*)(vrow + (4 * g + 48) * 2);
            oacc[cs] = __builtin_amdgcn_mfma_f32_16x16x32_f16(pa0, mkb(a0v, a1v), oacc[cs], 0, 0, 0);
            oacc[cs] = __builtin_amdgcn_mfma_f32_16x16x32_f16(pa1, mkb(b0v, b1v), oacc[cs], 0, 0, 0);
        }
    };

    const int jt0 = s * 16;
    loadK(kfA, jt0);
    for (int t = 0; t < 16; t += 2) {
        tile(kfA, kfB, jt0 + t);
        tile(kfB, kfA, jt0 + t + 1);
    }

    // ---- combine partials across splits (2-round LDS tree) ----
    // slot k (0..7): oacc at smem + k*8192 (cs*1024 + lane*16 layout);
    // m,l at smem + ML_OFF + k*128 (m: ln*4, l: 64 + ln*4).
    auto storeSlot = [&](int k) {
        float* sp = (float*)(smem + k * 8192);
        #pragma unroll
        for (int cs = 0; cs < 8; ++cs)
            *(f32x4*)(sp + cs * 256 + lane * 4) = oacc[cs];
        if (g == 0) {
            float* mlp = (float*)(smem + ML_OFF + k * 128);
            mlp[ln] = m_run;
            mlp[16 + ln] = l_run;
        }
    };
    auto mergeSlot = [&](int k) {
        const float* sp  = (const float*)(smem + k * 8192);
        const float* mlp = (const float*)(smem + ML_OFF + k * 128);
        const float mb = mlp[ln];
        const float lb = mlp[16 + ln];
        const float mn = fmaxf(m_run, mb);
        const float fa = __expf(m_run - mn);
        const float fb = __expf(mb - mn);
        l_run = fa * l_run + fb * lb;
        m_run = mn;
        const float fa0 = __shfl(fa, 4 * g + 0), fb0 = __shfl(fb, 4 * g + 0);
        const float fa1 = __shfl(fa, 4 * g + 1), fb1 = __shfl(fb, 4 * g + 1);
        const float fa2 = __shfl(fa, 4 * g + 2), fb2 = __shfl(fb, 4 * g + 2);
        const float fa3 = __shfl(fa, 4 * g + 3), fb3 = __shfl(fb, 4 * g + 3);
        #pragma unroll
        for (int cs = 0; cs < 8; ++cs) {
            f32x4 ob = *(const f32x4*)(sp + cs * 256 + lane * 4);
            oacc[cs][0] = fa0 * oacc[cs][0] + fb0 * ob[0];
            oacc[cs][1] = fa1 * oacc[cs][1] + fb1 * ob[1];
            oacc[cs][2] = fa2 * oacc[cs][2] + fb2 * ob[2];
            oacc[cs][3] = fa3 * oacc[cs][3] + fb3 * ob[3];
        }
    };

    __syncthreads();                       // Vs buffers dead from here
    if (s >= 2) storeSlot((s - 2) * 4 + qw);
    __syncthreads();
    if (s < 2)  mergeSlot(s * 4 + qw);
    __syncthreads();
    if (s == 1) storeSlot(qw);
    __syncthreads();
    if (s == 0) {
        mergeSlot(qw);
        // Epilogue: out[b][c][i], rows i = wib+4g+r, col c = cs*16+ln
        const float lr = 1.f / l_run;
        const float l0 = __shfl(lr, 4 * g + 0);
        const float l1 = __shfl(lr, 4 * g + 1);
        const float l2 = __shfl(lr, 4 * g + 2);
        const float l3 = __shfl(lr, 4 * g + 3);
        float* ob = out + (size_t)b * Cn * Nn;
        #pragma unroll
        for (int cs = 0; cs < 8; ++cs) {
            float4 o;
            o.x = oacc[cs][0] * l0;
            o.y = oacc[cs][1] * l1;
            o.z = oacc[cs][2] * l2;
            o.w = oacc[cs][3] * l3;
            *(float4*)&ob[(size_t)(cs * 16 + ln) * Nn + wib + 4 * g] = o;
        }
    }
}

extern "C" void kernel_launch(void* const* d_in, const int* in_sizes, int n_in,
                              void* d_out, int out_size, void* d_ws, size_t ws_size,
                              hipStream_t stream) {
    const float* x  = (const float*)d_in[0];
    const float* Wq = (const float*)d_in[1];
    const float* bq = (const float*)d_in[2];
    const float* Wk = (const float*)d_in[3];
    const float* bk = (const float*)d_in[4];
    const float* Wv = (const float*)d_in[5];
    const float* bv = (const float*)d_in[6];
    float* out = (float*)d_out;

    _Float16* ws = (_Float16*)d_ws;
    _Float16* Qh = ws;
    _Float16* Kh = ws + 1048576;
    _Float16* Vt = ws + 2097152;

    dim3 gproj(Nn / 64, 4, Bn);
    qkv_proj<<<gproj, 256, 0, stream>>>(x, Wq, bq, Wk, bk, Wv, bv, Qh, Kh, Vt);

    dim3 gattn(Nn / 64, Bn);
    attn_mfma<<<gattn, 1024, 4 * VS_BUFB, stream>>>(Qh, Kh, Vt, out);
}

// Round 6
// 152.642 us; speedup vs baseline: 1.6502x; 1.6474x over previous
//
#include <hip/hip_runtime.h>

// Problem constants
#define Bn  4
#define Cn  128
#define CQn 64
#define Nn  4096

typedef _Float16 h8_t __attribute__((ext_vector_type(8)));
typedef float    f32x4 __attribute__((ext_vector_type(4)));
typedef unsigned int u32;
typedef u32      u32x2 __attribute__((ext_vector_type(2)));

// ws layout (halves):
//  Qh: [B][N][64]   offset 0        (1,048,576)
//  Kh: [B][N][64]   offset 1048576  (1,048,576)
//  Vt: [B][128][N]  offset 2097152  (2,097,152)   (V transposed: [C][N])

// ---------------------------------------------------------------------------
// Kernel 1: fused QKV projection (fp32 compute, f16 outputs in attn layouts)
// ---------------------------------------------------------------------------
__global__ __launch_bounds__(256) void qkv_proj(
    const float* __restrict__ x,
    const float* __restrict__ Wq, const float* __restrict__ bq,
    const float* __restrict__ Wk, const float* __restrict__ bk,
    const float* __restrict__ Wv, const float* __restrict__ bv,
    _Float16* __restrict__ Qh, _Float16* __restrict__ Kh, _Float16* __restrict__ Vt)
{
    const int ntile = blockIdx.x;
    const int otile = blockIdx.y;
    const int b     = blockIdx.z;
    const int tid   = threadIdx.x;
    const int nbase = ntile * 64;

    __shared__ float Ws[64][132];
    __shared__ float Xs[128][68];

    const float* Wsrc; const float* bsrc; int obase;
    if (otile == 0)      { Wsrc = Wq;                     bsrc = bq;      obase = 0; }
    else if (otile == 1) { Wsrc = Wk;                     bsrc = bk;      obase = 0; }
    else                 { Wsrc = Wv + (otile - 2) * 64 * Cn;
                           bsrc = bv + (otile - 2) * 64;  obase = (otile - 2) * 64; }

    for (int u = 0; u < 8; ++u) {
        int f = tid + u * 256;
        int row = f >> 5;
        int col = (f & 31) * 4;
        *(float4*)&Ws[row][col] = *(const float4*)&Wsrc[row * Cn + col];
    }
    const float* xb = x + ((size_t)b * Cn) * Nn + nbase;
    for (int u = 0; u < 8; ++u) {
        int f = tid + u * 256;
        int c = f >> 4;
        int n = (f & 15) * 4;
        *(float4*)&Xs[c][n] = *(const float4*)&xb[(size_t)c * Nn + n];
    }
    __syncthreads();

    const int o0 = (tid >> 4) * 4;
    const int n0 = (tid & 15) * 4;
    float acc[4][4] = {};

    for (int c = 0; c < Cn; c += 4) {
        float4 w4[4], x4[4];
        for (int oo = 0; oo < 4; ++oo) w4[oo] = *(const float4*)&Ws[o0 + oo][c];
        for (int cc = 0; cc < 4; ++cc) x4[cc] = *(const float4*)&Xs[c + cc][n0];
        for (int oo = 0; oo < 4; ++oo) {
            const float* wv = (const float*)&w4[oo];
            for (int cc = 0; cc < 4; ++cc) {
                const float wsv = wv[cc];
                const float* xp = (const float*)&x4[cc];
                acc[oo][0] += wsv * xp[0];
                acc[oo][1] += wsv * xp[1];
                acc[oo][2] += wsv * xp[2];
                acc[oo][3] += wsv * xp[3];
            }
        }
    }

    float bias[4];
    for (int oo = 0; oo < 4; ++oo) bias[oo] = bsrc[o0 + oo];

    union H4 { _Float16 e[4]; short4 v; };

    if (otile <= 1) {
        _Float16* dst = (otile == 0 ? Qh : Kh) + ((size_t)b * Nn + nbase) * CQn;
        for (int nn = 0; nn < 4; ++nn) {
            H4 h;
            for (int oo = 0; oo < 4; ++oo) h.e[oo] = (_Float16)(acc[oo][nn] + bias[oo]);
            *(short4*)&dst[(size_t)(n0 + nn) * CQn + o0] = h.v;
        }
    } else {
        _Float16* dst = Vt + (size_t)b * Cn * Nn;
        const int og = obase + o0;
        for (int oo = 0; oo < 4; ++oo) {
            H4 h;
            for (int nn = 0; nn < 4; ++nn) h.e[nn] = (_Float16)(acc[oo][nn] + bias[oo]);
            *(short4*)&dst[(size_t)(og + oo) * Nn + nbase + n0] = h.v;
        }
    }
}

// ---------------------------------------------------------------------------
// Kernel 2: MFMA flash attention with intra-block 4-way KV split.
// 1024 threads = 16 waves = 4 query-waves (qw) x 4 splits (s).
// __launch_bounds__(1024, 1): min 1 BLOCK per CU (CUDA semantics of arg 2;
// rounds 4/5 showed (1024)/(1024,4) both resolve to 8 waves/EU -> 64-VGPR cap
// -> catastrophic spill, 465 MB scratch writes). 1 block/CU -> 4 waves/EU ->
// 128-reg cap. K single-buffered (-16 VGPR) to fit under the cap.
// Wave (qw,s): queries [blk*64 + 16qw, +16), j-tiles [16s, 16s+16).
// Swapped QK^T (D = S^T, col=query=ln). PV pairs P and V through the same
// kappa(e,g) slot map (correct for any HW k-map). End: 2-round LDS tree
// combine of (m, l, oacc) across splits, s=0 writes out.
// Dynamic LDS: 4 x 17408 B V buffers; combine overlays the same memory.
// ---------------------------------------------------------------------------
__device__ __forceinline__ h8_t mkb(u32x2 lo, u32x2 hi) {
    union { h8_t h; u32 u[4]; } t;
    t.u[0] = lo[0]; t.u[1] = lo[1]; t.u[2] = hi[0]; t.u[3] = hi[1];
    return t.h;
}

#define VS_STRIDE 136            // bytes per V row (68 halves)
#define VS_BUFB   17408          // 128 * 136
#define ML_OFF    65536          // ml scratch offset (overlays Vs buf 3 tail)

__global__ __launch_bounds__(1024, 1) void attn_mfma(
    const _Float16* __restrict__ Qh, const _Float16* __restrict__ Kh,
    const _Float16* __restrict__ Vt, float* __restrict__ out)
{
    extern __shared__ __align__(16) char smem[];

    const int tid  = threadIdx.x;
    const int w    = tid >> 6;
    const int qw   = w & 3;          // query-wave
    const int s    = w >> 2;         // kv split
    const int lane = tid & 63;
    const int g    = lane >> 4;
    const int ln   = lane & 15;
    const int b    = blockIdx.y;
    const int wib  = blockIdx.x * 64 + qw * 16;

    char* VsB = smem + s * VS_BUFB;  // this split's V buffer

    // Persistent Q fragments (B operand: col=ln -> query wib+ln)
    const _Float16* qrow = Qh + ((size_t)(b * Nn + wib + ln)) * CQn + 8 * g;
    const h8_t q0 = *(const h8_t*)(qrow);
    const h8_t q1 = *(const h8_t*)(qrow + 32);

    const _Float16* Kb  = Kh + (size_t)b * Nn * CQn;
    const _Float16* Vtb = Vt + (size_t)b * Cn * Nn;

    f32x4 oacc[8];
    #pragma unroll
    for (int i = 0; i < 8; ++i) oacc[i] = (f32x4){0.f, 0.f, 0.f, 0.f};
    float m_run = -3.0e38f, l_run = 0.f;

    // V staging coords within this split group (4 waves = 256 threads)
    const int gtid = qw * 64 + lane;

    auto tile = [&](int jt) {
        const int jbase = jt * 64;

        // 1) K fragments for this tile (single-buffered; issued first so the
        //    scores MFMA waits only on these, not on the V loads behind them)
        h8_t kf[4][2];
        const _Float16* kbase = Kb + ((size_t)(jbase + ln)) * CQn + 8 * g;
        #pragma unroll
        for (int js = 0; js < 4; ++js) {
            kf[js][0] = *(const h8_t*)(kbase + js * 16 * CQn);
            kf[js][1] = *(const h8_t*)(kbase + js * 16 * CQn + 32);
        }

        // 2) V-stage global loads (complete under scores+softmax)
        float4 vr[4];
        const _Float16* vg = Vtb + jbase;
        #pragma unroll
        for (int u = 0; u < 4; ++u) {
            int f = gtid + u * 256;
            vr[u] = *(const float4*)(vg + (size_t)(f >> 3) * Nn + (f & 7) * 8);
        }

        // 3) scores: st[js] rows = keys js*16+4g+r, col = query ln
        f32x4 st[4];
        #pragma unroll
        for (int js = 0; js < 4; ++js) {
            st[js] = (f32x4){0.f, 0.f, 0.f, 0.f};
            st[js] = __builtin_amdgcn_mfma_f32_16x16x32_f16(kf[js][0], q0, st[js], 0, 0, 0);
            st[js] = __builtin_amdgcn_mfma_f32_16x16x32_f16(kf[js][1], q1, st[js], 0, 0, 0);
        }

        // 4) online softmax (per query = per ln, replicated over g)
        float tmax = st[0][0];
        #pragma unroll
        for (int js = 0; js < 4; ++js)
            #pragma unroll
            for (int r = 0; r < 4; ++r) tmax = fmaxf(tmax, st[js][r]);
        tmax = fmaxf(tmax, __shfl_xor(tmax, 16));
        tmax = fmaxf(tmax, __shfl_xor(tmax, 32));
        const float mnew = fmaxf(m_run, tmax);
        float ts = 0.f;
        #pragma unroll
        for (int js = 0; js < 4; ++js)
            #pragma unroll
            for (int r = 0; r < 4; ++r) {
                float p = __expf(st[js][r] - mnew);
                st[js][r] = p;
                ts += p;
            }
        ts += __shfl_xor(ts, 16);
        ts += __shfl_xor(ts, 32);
        const float alpha = __expf(m_run - mnew);
        l_run = l_run * alpha + ts;
        m_run = mnew;

        const float a0 = __shfl(alpha, 4 * g + 0);
        const float a1 = __shfl(alpha, 4 * g + 1);
        const float a2 = __shfl(alpha, 4 * g + 2);
        const float a3 = __shfl(alpha, 4 * g + 3);
        #pragma unroll
        for (int cs = 0; cs < 8; ++cs) {
            oacc[cs][0] *= a0; oacc[cs][1] *= a1;
            oacc[cs][2] *= a2; oacc[cs][3] *= a3;
        }

        // P fragments by kappa(e,g) = 4g+(e&3)+16*(e>>2)
        union H8 { h8_t h; _Float16 e[8]; };
        H8 p0u, p1u;
        #pragma unroll
        for (int r = 0; r < 4; ++r) {
            p0u.e[r]     = (_Float16)st[0][r];
            p0u.e[4 + r] = (_Float16)st[1][r];
            p1u.e[r]     = (_Float16)st[2][r];
            p1u.e[4 + r] = (_Float16)st[3][r];
        }
        const h8_t pa0 = p0u.h;
        const h8_t pa1 = p1u.h;

        // 5) stage V tile into this split's LDS buffer
        __syncthreads();
        #pragma unroll
        for (int u = 0; u < 4; ++u) {
            int f = gtid + u * 256;
            *(float4*)(VsB + (size_t)(f >> 3) * VS_STRIDE + (f & 7) * 16) = vr[u];
        }
        __syncthreads();

        // 6) PV: per c-subtile, gather B-fragments by the same kappa map
        #pragma unroll
        for (int cs = 0; cs < 8; ++cs) {
            const char* vrow = VsB + (size_t)(cs * 16 + ln) * VS_STRIDE;
            u32x2 a0v = *(const u32x2*)(vrow + (4 * g) * 2);
            u32x2 a1v = *(const u32x2*)(vrow + (4 * g + 16) * 2);
            u32x2 b0v = *(const u32x2*)(vrow + (4 * g + 32) * 2);
            u32x2 b1v = *(const u32x2*)(vrow + (4 * g + 48) * 2);
            oacc[cs] = __builtin_amdgcn_mfma_f32_16x16x32_f16(pa0, mkb(a0v, a1v), oacc[cs], 0, 0, 0);
            oacc[cs] = __builtin_amdgcn_mfma_f32_16x16x32_f16(pa1, mkb(b0v, b1v), oacc[cs], 0, 0, 0);
        }
    };

    const int jt0 = s * 16;
    for (int t = 0; t < 16; ++t) tile(jt0 + t);

    // ---- combine partials across splits (2-round LDS tree) ----
    // slot k (0..7): oacc at smem + k*8192 (cs*1024 + lane*16 layout);
    // m,l at smem + ML_OFF + k*128 (m: ln*4, l: 64 + ln*4).
    auto storeSlot = [&](int k) {
        float* sp = (float*)(smem + k * 8192);
        #pragma unroll
        for (int cs = 0; cs < 8; ++cs)
            *(f32x4*)(sp + cs * 256 + lane * 4) = oacc[cs];
        if (g == 0) {
            float* mlp = (float*)(smem + ML_OFF + k * 128);
            mlp[ln] = m_run;
            mlp[16 + ln] = l_run;
        }
    };
    auto mergeSlot = [&](int k) {
        const float* sp  = (const float*)(smem + k * 8192);
        const float* mlp = (const float*)(smem + ML_OFF + k * 128);
        const float mb = mlp[ln];
        const float lb = mlp[16 + ln];
        const float mn = fmaxf(m_run, mb);
        const float fa = __expf(m_run - mn);
        const float fb = __expf(mb - mn);
        l_run = fa * l_run + fb * lb;
        m_run = mn;
        const float fa0 = __shfl(fa, 4 * g + 0), fb0 = __shfl(fb, 4 * g + 0);
        const float fa1 = __shfl(fa, 4 * g + 1), fb1 = __shfl(fb, 4 * g + 1);
        const float fa2 = __shfl(fa, 4 * g + 2), fb2 = __shfl(fb, 4 * g + 2);
        const float fa3 = __shfl(fa, 4 * g + 3), fb3 = __shfl(fb, 4 * g + 3);
        #pragma unroll
        for (int cs = 0; cs < 8; ++cs) {
            f32x4 ob = *(const f32x4*)(sp + cs * 256 + lane * 4);
            oacc[cs][0] = fa0 * oacc[cs][0] + fb0 * ob[0];
            oacc[cs][1] = fa1 * oacc[cs][1] + fb1 * ob[1];
            oacc[cs][2] = fa2 * oacc[cs][2] + fb2 * ob[2];
            oacc[cs][3] = fa3 * oacc[cs][3] + fb3 * ob[3];
        }
    };

    __syncthreads();                       // Vs buffers dead from here
    if (s >= 2) storeSlot((s - 2) * 4 + qw);
    __syncthreads();
    if (s < 2)  mergeSlot(s * 4 + qw);
    __syncthreads();
    if (s == 1) storeSlot(qw);
    __syncthreads();
    if (s == 0) {
        mergeSlot(qw);
        // Epilogue: out[b][c][i], rows i = wib+4g+r, col c = cs*16+ln
        const float lr = 1.f / l_run;
        const float l0 = __shfl(lr, 4 * g + 0);
        const float l1 = __shfl(lr, 4 * g + 1);
        const float l2 = __shfl(lr, 4 * g + 2);
        const float l3 = __shfl(lr, 4 * g + 3);
        float* ob = out + (size_t)b * Cn * Nn;
        #pragma unroll
        for (int cs = 0; cs < 8; ++cs) {
            float4 o;
            o.x = oacc[cs][0] * l0;
            o.y = oacc[cs][1] * l1;
            o.z = oacc[cs][2] * l2;
            o.w = oacc[cs][3] * l3;
            *(float4*)&ob[(size_t)(cs * 16 + ln) * Nn + wib + 4 * g] = o;
        }
    }
}

extern "C" void kernel_launch(void* const* d_in, const int* in_sizes, int n_in,
                              void* d_out, int out_size, void* d_ws, size_t ws_size,
                              hipStream_t stream) {
    const float* x  = (const float*)d_in[0];
    const float* Wq = (const float*)d_in[1];
    const float* bq = (const float*)d_in[2];
    const float* Wk = (const float*)d_in[3];
    const float* bk = (const float*)d_in[4];
    const float* Wv = (const float*)d_in[5];
    const float* bv = (const float*)d_in[6];
    float* out = (float*)d_out;

    _Float16* ws = (_Float16*)d_ws;
    _Float16* Qh = ws;
    _Float16* Kh = ws + 1048576;
    _Float16* Vt = ws + 2097152;

    dim3 gproj(Nn / 64, 4, Bn);
    qkv_proj<<<gproj, 256, 0, stream>>>(x, Wq, bq, Wk, bk, Wv, bv, Qh, Kh, Vt);

    dim3 gattn(Nn / 64, Bn);
    attn_mfma<<<gattn, 1024, 4 * VS_BUFB, stream>>>(Qh, Kh, Vt, out);
}